// Round 8
// baseline (385.787 us; speedup 1.0000x reference)
//
#include <hip/hip_runtime.h>
#include <hip/hip_bf16.h>

typedef __hip_bfloat16 bf16_t;
typedef __bf16 bf16x8 __attribute__((ext_vector_type(8)));
typedef float f32x4 __attribute__((ext_vector_type(4)));

__device__ __forceinline__ void gload_lds16(const void* g, void* l) {
  __builtin_amdgcn_global_load_lds(
      (const __attribute__((address_space(1))) void*)g,
      (__attribute__((address_space(3))) void*)l, 16, 0, 0);
}

__device__ __forceinline__ unsigned short f2bf(float f) {
  bf16_t h = __float2bfloat16(f);
  return reinterpret_cast<unsigned short&>(h);
}

// ---------------- weight transpose: fp32 [K][N] -> bf16 [N][K] ----------------
__global__ __launch_bounds__(256) void wtrans_kernel(
    const float* __restrict__ in, bf16_t* __restrict__ out, int K, int N) {
  __shared__ float tile[32][33];
  int tx = threadIdx.x, ty = threadIdx.y;
  int n = blockIdx.x * 32 + tx;
  int k0 = blockIdx.y * 32 + ty;
#pragma unroll
  for (int j = 0; j < 32; j += 8) tile[ty + j][tx] = in[(size_t)(k0 + j) * N + n];
  __syncthreads();
  int k = blockIdx.y * 32 + tx;
  int n0 = blockIdx.x * 32 + ty;
#pragma unroll
  for (int j = 0; j < 32; j += 8)
    out[(size_t)(n0 + j) * K + k] = __float2bfloat16(tile[tx][ty + j]);
}

// ---------------- LayerNorm (+ optional pos_emb) -> bf16 ----------------
__global__ __launch_bounds__(256) void ln_kernel(
    const float* __restrict__ x, const float* __restrict__ g,
    const float* __restrict__ b, const float* __restrict__ pos,
    bf16_t* __restrict__ out, int S) {
  int row = blockIdx.x;
  int tid = threadIdx.x;
  const float4* xr = (const float4*)(x + (size_t)row * 1024);
  float4 v = xr[tid];
  float s1 = v.x + v.y + v.z + v.w;
  float s2 = v.x * v.x + v.y * v.y + v.z * v.z + v.w * v.w;
#pragma unroll
  for (int off = 1; off < 64; off <<= 1) {
    s1 += __shfl_xor(s1, off);
    s2 += __shfl_xor(s2, off);
  }
  __shared__ float red[2][4];
  int w = tid >> 6;
  if ((tid & 63) == 0) { red[0][w] = s1; red[1][w] = s2; }
  __syncthreads();
  s1 = red[0][0] + red[0][1] + red[0][2] + red[0][3];
  s2 = red[1][0] + red[1][1] + red[1][2] + red[1][3];
  float mu = s1 * (1.f / 1024.f);
  float var = s2 * (1.f / 1024.f) - mu * mu;
  float rs = rsqrtf(var + 1e-5f);
  float4 gg = ((const float4*)g)[tid];
  float4 bb = ((const float4*)b)[tid];
  float4 pp = {0.f, 0.f, 0.f, 0.f};
  if (pos) pp = ((const float4*)(pos + (size_t)(row & (S - 1)) * 1024))[tid];
  ushort4 o4;
  o4.x = f2bf((v.x - mu) * rs * gg.x + bb.x + pp.x);
  o4.y = f2bf((v.y - mu) * rs * gg.y + bb.y + pp.y);
  o4.z = f2bf((v.z - mu) * rs * gg.z + bb.z + pp.z);
  o4.w = f2bf((v.w - mu) * rs * gg.w + bb.w + pp.w);
  ((ushort4*)(out + (size_t)row * 1024))[tid] = o4;
}

// ---------------- 256x256 4-phase GEMM (T3+T4): C = A * BT^T + bias ----------------
// 512 threads = 8 waves (2M x 4N), per-wave 128x64 out. BK=64, 128KB LDS dbuf.
// Counted vmcnt: group top issues next-tile A-halves then vmcnt(4) (drains the
// previous tile's 8 loads, keeps 4 in flight); B-halves staged in phases 0,1.
// Phases: quadrant (mh,nh): 12 ds_read_b128 + stage -> barrier -> setprio MFMA
// -> barrier. EPI: 0 = QKV scatter, 2 = gelu -> bf16.
template <int EPI>
__global__ __launch_bounds__(512, 2) void gemm256(
    const bf16_t* __restrict__ A, const bf16_t* __restrict__ BT,
    const float* __restrict__ bias, bf16_t* __restrict__ outb,
    bf16_t* __restrict__ qb, bf16_t* __restrict__ kb, bf16_t* __restrict__ vb,
    int M, int N, int K) {
  __shared__ char lds[131072];
  int tid = threadIdx.x;
  int l = tid & 63, w = tid >> 6;
  int wr = w >> 2, wc = w & 3;  // 2 x 4 waves
  int ll = l & 15, lg = l >> 4;
  // T1 chunked XCD swizzle (grid %8 == 0)
  int chunk = gridDim.x >> 3;
  int swz = (blockIdx.x & 7) * chunk + (blockIdx.x >> 3);
  int nbx = N >> 8;
  int bx = swz % nbx, by = swz / nbx;
  int rowBase = by * 256, colBase = bx * 256;

  f32x4 acc[8][4];
  f32x4 z = {0.f, 0.f, 0.f, 0.f};
#pragma unroll
  for (int i = 0; i < 8; i++)
#pragma unroll
    for (int j = 0; j < 4; j++) acc[i][j] = z;

  // stage one 16KB half-tile: h = 0,1 -> A rows 0-127 / 128-255; 2,3 -> B same
  auto SHALF = [&](int kt, int c, int h) {
    const bf16_t* src = (h < 2) ? A : BT;
    int base = (h < 2) ? rowBase : colBase;
    char* dst = lds + c * 65536 + ((h < 2) ? 0 : 32768);
    int tileoff = (h & 1) * 16384;
#pragma unroll
    for (int i = 0; i < 2; i++) {
      int p = tileoff + i * 8192 + tid * 16;
      int o = p ^ (((p >> 7) & 7) << 4);
      int r = o >> 7, cc = (o & 127) >> 1;
      gload_lds16(src + (size_t)(base + r) * K + kt * 64 + cc, dst + p);
    }
  };

  int nkt = K >> 6;
  // prologue: full tile 0 into buf 0
#pragma unroll
  for (int h = 0; h < 4; h++) SHALF(0, 0, h);

  for (int t = 0; t < nkt; ++t) {
    int c = t & 1;
    bool more = (t + 1 < nkt);
    if (more) {
      SHALF(t + 1, c ^ 1, 0);
      SHALF(t + 1, c ^ 1, 1);
      asm volatile("s_waitcnt vmcnt(4)" ::: "memory");  // tile t fully landed
    } else {
      asm volatile("s_waitcnt vmcnt(0)" ::: "memory");
    }
    __builtin_amdgcn_s_barrier();  // buf c valid for all waves
    asm volatile("" ::: "memory");
    char* Ab = lds + c * 65536;
    char* Bb = Ab + 32768;

#pragma unroll
    for (int ph = 0; ph < 4; ++ph) {
      int mh = ph >> 1, nh = ph & 1;
      bf16x8 af[4][2], bfv[2][2];
#pragma unroll
      for (int q = 0; q < 4; q++) {
        int row = wr * 128 + (mh * 4 + q) * 16 + ll;
#pragma unroll
        for (int kk = 0; kk < 2; kk++) {
          int o = (row << 7) + (kk << 6) + (lg << 4);
          af[q][kk] = *(const bf16x8*)(Ab + (o ^ ((row & 7) << 4)));
        }
      }
#pragma unroll
      for (int n = 0; n < 2; n++) {
        int row = wc * 64 + (nh * 2 + n) * 16 + ll;
#pragma unroll
        for (int kk = 0; kk < 2; kk++) {
          int o = (row << 7) + (kk << 6) + (lg << 4);
          bfv[n][kk] = *(const bf16x8*)(Bb + (o ^ ((row & 7) << 4)));
        }
      }
      if (more && ph < 2) SHALF(t + 1, c ^ 1, 2 + ph);  // B halves
      __builtin_amdgcn_s_barrier();
      __builtin_amdgcn_s_setprio(1);
#pragma unroll
      for (int q = 0; q < 4; q++)
#pragma unroll
        for (int n = 0; n < 2; n++)
#pragma unroll
          for (int kk = 0; kk < 2; kk++)
            acc[mh * 4 + q][nh * 2 + n] = __builtin_amdgcn_mfma_f32_16x16x32_bf16(
                af[q][kk], bfv[n][kk], acc[mh * 4 + q][nh * 2 + n], 0, 0, 0);
      __builtin_amdgcn_s_setprio(0);
      __builtin_amdgcn_s_barrier();
    }
  }

  // epilogue
#pragma unroll
  for (int mi = 0; mi < 8; mi++) {
#pragma unroll
    for (int ni = 0; ni < 4; ni++) {
#pragma unroll
      for (int j = 0; j < 4; j++) {
        int grow = rowBase + wr * 128 + mi * 16 + lg * 4 + j;
        int gcol = colBase + wc * 64 + ni * 16 + ll;
        float v = acc[mi][ni][j] + bias[gcol];
        if (EPI == 0) {
          int bb = grow >> 11, s = grow & 2047;
          int tq = gcol >> 10, rem = gcol & 1023;
          int h = rem >> 6, d = rem & 63;
          size_t bh = (size_t)(bb * 16 + h);
          if (tq == 0)
            qb[(bh * 2048 + s) * 64 + d] = __float2bfloat16(v);
          else if (tq == 1)
            kb[(bh * 2048 + s) * 64 + d] = __float2bfloat16(v);
          else
            vb[(bh * 64 + d) * 2048 + s] = __float2bfloat16(v);
        } else {
          float c3 = v * v * v;
          float tt = tanhf(0.7978845608028654f * (v + 0.044715f * c3));
          outb[(size_t)grow * N + gcol] = __float2bfloat16(0.5f * v * (1.f + tt));
        }
      }
    }
  }
}

// ---------------- 128x128 GEMM (DBUF counted-vmcnt) for N=1024 outputs ----------------
// EPI 1: out_f32 = resid + acc + bias. 1-D grid, %8==0, XCD swizzle.
template <int EPI, int DBUF>
__global__ __launch_bounds__(256) void gemm_bt(
    const bf16_t* __restrict__ A, const bf16_t* __restrict__ BT,
    const float* __restrict__ bias, const float* __restrict__ resid,
    float* __restrict__ outf, int M, int N, int K) {
  __shared__ char lds[DBUF ? 65536 : 32768];
  int tid = threadIdx.x;
  int l = tid & 63;
  int w = tid >> 6;
  int wr = w >> 1, wc = w & 1;
  int ll = l & 15, lg = l >> 4;
  int chunk = gridDim.x >> 3;
  int swz = (blockIdx.x & 7) * chunk + (blockIdx.x >> 3);
  int nbx = N >> 7;
  int bx = swz % nbx, by = swz / nbx;
  int rowBase = by * 128, colBase = bx * 128;

  f32x4 acc[4][4];
  f32x4 z = {0.f, 0.f, 0.f, 0.f};
#pragma unroll
  for (int i = 0; i < 4; i++)
#pragma unroll
    for (int j = 0; j < 4; j++) acc[i][j] = z;

  auto STAGE = [&](int kt, int c) {
#pragma unroll
    for (int i = 0; i < 4; i++) {
      int p = i * 4096 + tid * 16;
      int o = p ^ (((p >> 7) & 7) << 4);
      int r = o >> 7, cc = (o & 127) >> 1;
      gload_lds16(A + (size_t)(rowBase + r) * K + kt * 64 + cc, lds + c * 32768 + p);
    }
#pragma unroll
    for (int i = 0; i < 4; i++) {
      int p = i * 4096 + tid * 16;
      int o = p ^ (((p >> 7) & 7) << 4);
      int r = o >> 7, cc = (o & 127) >> 1;
      gload_lds16(BT + (size_t)(colBase + r) * K + kt * 64 + cc,
                  lds + c * 32768 + 16384 + p);
    }
  };

  int nkt = K >> 6;
  if (DBUF) STAGE(0, 0);
  int cbuf = 0;
  for (int kt = 0; kt < nkt; ++kt) {
    if (DBUF) {
      __builtin_amdgcn_s_barrier();
      if (kt + 1 < nkt) {
        STAGE(kt + 1, cbuf ^ 1);
        asm volatile("s_waitcnt vmcnt(8)" ::: "memory");
      } else {
        asm volatile("s_waitcnt vmcnt(0)" ::: "memory");
      }
      __builtin_amdgcn_s_barrier();
      asm volatile("" ::: "memory");
    } else {
      __syncthreads();
      STAGE(kt, 0);
      __syncthreads();
    }
    char* Ab = lds + cbuf * 32768;
    char* Bb = Ab + 16384;

    bf16x8 af[4][2], bfv[4][2];
#pragma unroll
    for (int mi = 0; mi < 4; mi++) {
      int row = wr * 64 + mi * 16 + ll;
#pragma unroll
      for (int kk = 0; kk < 2; kk++) {
        int o = (row << 7) + (kk << 6) + (lg << 4);
        af[mi][kk] = *(const bf16x8*)(Ab + (o ^ ((row & 7) << 4)));
      }
    }
#pragma unroll
    for (int ni = 0; ni < 4; ni++) {
      int row = wc * 64 + ni * 16 + ll;
#pragma unroll
      for (int kk = 0; kk < 2; kk++) {
        int o = (row << 7) + (kk << 6) + (lg << 4);
        bfv[ni][kk] = *(const bf16x8*)(Bb + (o ^ ((row & 7) << 4)));
      }
    }
#pragma unroll
    for (int mi = 0; mi < 4; mi++)
#pragma unroll
      for (int ni = 0; ni < 4; ni++)
#pragma unroll
        for (int kk = 0; kk < 2; kk++)
          acc[mi][ni] = __builtin_amdgcn_mfma_f32_16x16x32_bf16(
              af[mi][kk], bfv[ni][kk], acc[mi][ni], 0, 0, 0);
    if (DBUF) cbuf ^= 1;
  }

#pragma unroll
  for (int mi = 0; mi < 4; mi++) {
#pragma unroll
    for (int ni = 0; ni < 4; ni++) {
#pragma unroll
      for (int j = 0; j < 4; j++) {
        int grow = rowBase + wr * 64 + mi * 16 + lg * 4 + j;
        int gcol = colBase + wc * 64 + ni * 16 + ll;
        float v = acc[mi][ni][j] + bias[gcol];
        size_t idx = (size_t)grow * N + gcol;
        outf[idx] = resid[idx] + v;
      }
    }
  }
}

// ---------------- flash attention (causal), HD=64, 128-row Q tiles ----------------
__global__ __launch_bounds__(256, 2) void attn_kernel(
    const bf16_t* __restrict__ qb, const bf16_t* __restrict__ kb,
    const bf16_t* __restrict__ vbT, bf16_t* __restrict__ op, int S) {
  int id = blockIdx.x;
  int bh = id & 31;
  int qt = 15 - (id >> 5);  // heavy-first dispatch order
  int tid = threadIdx.x;
  int w = tid >> 6, l = tid & 63;
  int ll = l & 15, lg = l >> 4;
  __shared__ char lds[49152];
  char* Pw = lds + 32768 + w * 4096;

  int qbase = qt * 128;
  int qlo = qbase + w * 32;
  int qhi = qlo + 31;

  bf16x8 qf[2][2];
#pragma unroll
  for (int mi = 0; mi < 2; mi++) {
    const bf16_t* qrp = qb + ((size_t)bh * S + qbase + w * 32 + mi * 16 + ll) * 64;
#pragma unroll
    for (int kk = 0; kk < 2; kk++) qf[mi][kk] = *(const bf16x8*)(qrp + kk * 32 + lg * 8);
  }

  f32x4 Oacc[2][4];
  f32x4 z = {0.f, 0.f, 0.f, 0.f};
#pragma unroll
  for (int mi = 0; mi < 2; mi++)
#pragma unroll
    for (int i = 0; i < 4; i++) Oacc[mi][i] = z;
  float mrow[2], lrow[2];
#pragma unroll
  for (int mi = 0; mi < 2; mi++) { mrow[mi] = -INFINITY; lrow[mi] = 0.f; }

  int last = 2 * qt + 1;

  auto STAGE = [&](int kt, int c) {
    char* Kt = lds + c * 8192;
    char* Vt = lds + 16384 + c * 8192;
#pragma unroll
    for (int i = 0; i < 2; ++i) {
      int p = i * 4096 + tid * 16;
      int o = p ^ (((p >> 7) & 7) << 4);
      int r = o >> 7, cc = (o & 127) >> 1;
      gload_lds16(kb + ((size_t)bh * S + kt * 64 + r) * 64 + cc, Kt + p);
    }
#pragma unroll
    for (int i = 0; i < 2; ++i) {
      int p = i * 4096 + tid * 16;
      int o = p ^ (((p >> 7) & 7) << 4);
      int d = o >> 7, cc = (o & 127) >> 1;
      gload_lds16(vbT + ((size_t)bh * 64 + d) * S + kt * 64 + cc, Vt + p);
    }
  };

  STAGE(0, 0);
  int c = 0;
  for (int kt = 0; kt <= last; ++kt) {
    __builtin_amdgcn_s_barrier();
    if (kt < last) {
      STAGE(kt + 1, c ^ 1);
      asm volatile("s_waitcnt vmcnt(4)" ::: "memory");
    } else {
      asm volatile("s_waitcnt vmcnt(0)" ::: "memory");
    }
    __builtin_amdgcn_s_barrier();
    asm volatile("" ::: "memory");

    if (kt * 64 <= qhi) {
      char* Kt = lds + c * 8192;
      char* Vt = lds + 16384 + c * 8192;

      bf16x8 kf[4][2];
#pragma unroll
      for (int f = 0; f < 4; f++) {
        int row = f * 16 + ll;
#pragma unroll
        for (int kk = 0; kk < 2; kk++) {
          int o = (row << 7) + (kk << 6) + (lg << 4);
          kf[f][kk] = *(const bf16x8*)(Kt + (o ^ ((row & 7) << 4)));
        }
      }
      f32x4 sfr[2][4];
      __builtin_amdgcn_s_setprio(1);
#pragma unroll
      for (int mi = 0; mi < 2; mi++)
#pragma unroll
        for (int f = 0; f < 4; f++) {
          sfr[mi][f] = z;
#pragma unroll
          for (int kk = 0; kk < 2; kk++)
            sfr[mi][f] = __builtin_amdgcn_mfma_f32_16x16x32_bf16(
                kf[f][kk], qf[mi][kk], sfr[mi][f], 0, 0, 0);
        }
      __builtin_amdgcn_s_setprio(0);

      bool diag = (kt * 64 + 63) > qlo;
      float mx[2];
#pragma unroll
      for (int mi = 0; mi < 2; mi++) {
        int gq = qlo + mi * 16 + ll;
        float m_ = -INFINITY;
#pragma unroll
        for (int f = 0; f < 4; f++)
#pragma unroll
          for (int j = 0; j < 4; j++) {
            float s = sfr[mi][f][j] * 0.125f;
            if (diag && (kt * 64 + f * 16 + lg * 4 + j) > gq) s = -INFINITY;
            sfr[mi][f][j] = s;
            m_ = fmaxf(m_, s);
          }
        m_ = fmaxf(m_, __shfl_xor(m_, 16));
        m_ = fmaxf(m_, __shfl_xor(m_, 32));
        mx[mi] = m_;
      }

      bool ok = (mx[0] <= mrow[0] + 8.f) && (mx[1] <= mrow[1] + 8.f);
      if (!__all(ok)) {
#pragma unroll
        for (int mi = 0; mi < 2; mi++) {
          float mnew = fmaxf(mrow[mi], mx[mi]);
          float fj = __expf(mrow[mi] - mnew);
          mrow[mi] = mnew;
          lrow[mi] *= fj;
#pragma unroll
          for (int j = 0; j < 4; j++) {
            float frow = __shfl(fj, (lg << 2) + j);
#pragma unroll
            for (int fd = 0; fd < 4; fd++) Oacc[mi][fd][j] *= frow;
          }
        }
      }

#pragma unroll
      for (int mi = 0; mi < 2; mi++) {
        float sum = 0.f;
        int q = mi * 16 + ll;
#pragma unroll
        for (int f = 0; f < 4; f++) {
          float p0 = __expf(sfr[mi][f][0] - mrow[mi]);
          float p1 = __expf(sfr[mi][f][1] - mrow[mi]);
          float p2 = __expf(sfr[mi][f][2] - mrow[mi]);
          float p3 = __expf(sfr[mi][f][3] - mrow[mi]);
          sum += (p0 + p1) + (p2 + p3);
          uint2 pk;
          pk.x = (unsigned)f2bf(p0) | ((unsigned)f2bf(p1) << 16);
          pk.y = (unsigned)f2bf(p2) | ((unsigned)f2bf(p3) << 16);
          int o = (q << 7) + ((f * 16 + lg * 4) << 1);
          *(uint2*)(Pw + (o ^ ((q & 7) << 4))) = pk;
        }
        sum += __shfl_xor(sum, 16);
        sum += __shfl_xor(sum, 32);
        lrow[mi] += sum;
      }

      bf16x8 vf2[4][2];
#pragma unroll
      for (int fd = 0; fd < 4; fd++) {
        int row = fd * 16 + ll;
#pragma unroll
        for (int kk = 0; kk < 2; kk++) {
          int o = (row << 7) + (kk << 6) + (lg << 4);
          vf2[fd][kk] = *(const bf16x8*)(Vt + (o ^ ((row & 7) << 4)));
        }
      }
      bf16x8 pf[2][2];
#pragma unroll
      for (int mi = 0; mi < 2; mi++) {
        int pr = mi * 16 + ll;
#pragma unroll
        for (int kk = 0; kk < 2; kk++) {
          int o = (pr << 7) + (kk << 6) + (lg << 4);
          pf[mi][kk] = *(const bf16x8*)(Pw + (o ^ ((pr & 7) << 4)));
        }
      }
      __builtin_amdgcn_s_setprio(1);
#pragma unroll
      for (int mi = 0; mi < 2; mi++)
#pragma unroll
        for (int fd = 0; fd < 4; fd++)
#pragma unroll
          for (int kk = 0; kk < 2; kk++)
            Oacc[mi][fd] = __builtin_amdgcn_mfma_f32_16x16x32_bf16(
                pf[mi][kk], vf2[fd][kk], Oacc[mi][fd], 0, 0, 0);
      __builtin_amdgcn_s_setprio(0);
    }
    c ^= 1;
  }

  int b = bh >> 4, hh = bh & 15;
#pragma unroll
  for (int mi = 0; mi < 2; mi++) {
    float invA = 1.f / lrow[mi];
#pragma unroll
    for (int j = 0; j < 4; j++) {
      float inv = __shfl(invA, (lg << 2) + j);
      int srow = qbase + w * 32 + mi * 16 + lg * 4 + j;
#pragma unroll
      for (int fd = 0; fd < 4; fd++) {
        int col = (hh << 6) + (fd << 4) + ll;
        op[((size_t)b * S + srow) * 1024 + col] = __float2bfloat16(Oacc[mi][fd][j] * inv);
      }
    }
  }
}

// ---------------- launch ----------------
extern "C" void kernel_launch(void* const* d_in, const int* in_sizes, int n_in,
                              void* d_out, int out_size, void* d_ws, size_t ws_size,
                              hipStream_t stream) {
  const float* x = (const float*)d_in[0];
  const float* pos_emb = (const float*)d_in[1];
  const float* ln1_g = (const float*)d_in[2];
  const float* ln1_b = (const float*)d_in[3];
  const float* w_qkv = (const float*)d_in[4];
  const float* b_qkv = (const float*)d_in[5];
  const float* w_o = (const float*)d_in[6];
  const float* b_o = (const float*)d_in[7];
  const float* ln2_g = (const float*)d_in[8];
  const float* ln2_b = (const float*)d_in[9];
  const float* w_fc = (const float*)d_in[10];
  const float* b_fc = (const float*)d_in[11];
  const float* w_proj = (const float*)d_in[12];
  const float* b_proj = (const float*)d_in[13];

  char* ws = (char*)d_ws;
  auto take = [&](size_t bytes) {
    char* p = ws;
    ws += (bytes + 255) & ~(size_t)255;
    return p;
  };
  bf16_t* wqkvT = (bf16_t*)take(3072ull * 1024 * 2);
  bf16_t* woT = (bf16_t*)take(1024ull * 1024 * 2);
  bf16_t* wfcT = (bf16_t*)take(4096ull * 1024 * 2);
  bf16_t* wprojT = (bf16_t*)take(1024ull * 4096 * 2);
  bf16_t* h = (bf16_t*)take(4096ull * 1024 * 2);
  bf16_t* qbuf = (bf16_t*)take(32ull * 2048 * 64 * 2);
  bf16_t* kbuf = (bf16_t*)take(32ull * 2048 * 64 * 2);
  bf16_t* vbuf = (bf16_t*)take(32ull * 2048 * 64 * 2);
  bf16_t* aout = (bf16_t*)take(4096ull * 1024 * 2);
  float* x2 = (float*)take(4096ull * 1024 * 4);
  bf16_t* mb = (bf16_t*)take(4096ull * 1024 * 2);
  bf16_t* fca = (bf16_t*)qbuf;  // aliases dead q/k/v/aout buffers (32MB)

  dim3 tb(32, 8);
  wtrans_kernel<<<dim3(3072 / 32, 1024 / 32), tb, 0, stream>>>(w_qkv, wqkvT, 1024, 3072);
  wtrans_kernel<<<dim3(1024 / 32, 1024 / 32), tb, 0, stream>>>(w_o, woT, 1024, 1024);
  wtrans_kernel<<<dim3(4096 / 32, 1024 / 32), tb, 0, stream>>>(w_fc, wfcT, 1024, 4096);
  wtrans_kernel<<<dim3(1024 / 32, 4096 / 32), tb, 0, stream>>>(w_proj, wprojT, 4096, 1024);

  ln_kernel<<<4096, 256, 0, stream>>>(x, ln1_g, ln1_b, pos_emb, h, 2048);

  gemm256<0><<<dim3(192), 512, 0, stream>>>(h, wqkvT, b_qkv, nullptr,
                                            qbuf, kbuf, vbuf, 4096, 3072, 1024);

  attn_kernel<<<dim3(512), 256, 0, stream>>>(qbuf, kbuf, vbuf, aout, 2048);

  gemm_bt<1, 1><<<dim3(256), 256, 0, stream>>>(aout, woT, b_o, x, x2,
                                               4096, 1024, 1024);

  ln_kernel<<<4096, 256, 0, stream>>>(x2, ln2_g, ln2_b, nullptr, mb, 2048);

  gemm256<2><<<dim3(256), 512, 0, stream>>>(mb, wfcT, b_fc, fca,
                                            nullptr, nullptr, nullptr, 4096, 4096, 1024);

  gemm_bt<1, 1><<<dim3(256), 256, 0, stream>>>(fca, wprojT, b_proj, x2, (float*)d_out,
                                               4096, 1024, 4096);
}